// Round 4
// baseline (740.922 us; speedup 1.0000x reference)
//
#include <hip/hip_runtime.h>
#include <stdint.h>

// ScaledDotProductAttention with per-neighbor prior reweighting + mask.
// Shapes: q,k,v [N=65536, L=20, D=64] f32; r_pri [B=32768, L]; mask [N, L] (int).
// out = concat(output [N,D], attn [N,L]) f32.
//
// R3 (kept): mask-predicated loads -- masked l has w[l]==0 exactly, skip its bytes.
// R6 (= hardened R5): VGPR-free load issue via global_load_lds into a 2-deep
// per-wave LDS ring (q,k), counted-vmcnt waits, 2048 persistent 1-wave blocks,
// 32 rows each. Hardening vs the R5 submission that coincided with a container
// failure:
//   - ALL predicated loads are BRANCHLESS: masked lanes' global addresses are
//     clamped (v_cndmask on the pointer) to a 1 KB dummy buffer (d_ws; L2-hot,
//     ~zero HBM). => every VMEM instruction always issues; vmcnt counts are
//     exec-independent and deterministic.
//   - v is loaded unconditionally from the clamped address, then value-selected
//     to 0 for masked chunks (ternary => v_cndmask; NaN garbage is discarded,
//     never touched by arithmetic that escapes the masked 16-lane group).
//   - Correctness does NOT hinge on the manual waits: in-order vmcnt semantics
//     mean the compiler's own counted waits for younger VGPR loads (meta/v)
//     drain every older global_load_lds stage before its buffer's ds_reads.
//     Manual waits (steady vmcnt(31)) only shape the schedule.
// Per-CU in flight: 8 waves x ~20 KB staged q/k  >>  ~22 KB Little's-law
// requirement for 6.3 TB/s at ~900 cy HBM latency.

namespace {
constexpr int kL = 20;
constexpr int kD = 64;
constexpr int kB = 32768;
constexpr float kNegInf = -1e10f;
constexpr float kInvTemp = 0.125f;  // 1 / TEMPERATURE(=8)
constexpr int kRowsPerWave = 32;
}

#define AS1 __attribute__((address_space(1)))
#define AS3 __attribute__((address_space(3)))

__device__ __forceinline__ void gld_lds16(const void* gsrc, void* ldst) {
    // one global_load_lds_dwordx4: lane i writes 16 B at ldst + i*16
    __builtin_amdgcn_global_load_lds((const AS1 void*)gsrc, (AS3 void*)ldst,
                                     16, 0, 0);
}

#define WAITCNT_SB(N) do {                                                     \
    asm volatile("s_waitcnt vmcnt(" #N ")" ::: "memory");                      \
    __builtin_amdgcn_sched_barrier(0);                                         \
} while (0)

// ---- meta load + ballot (10 vmem, unconditional) ----
#define LOAD_META_TO(MK, RP, AM, n) do {                                       \
    const int b_ = (n) & (kB - 1);                                             \
    const float* rp_ = r_pri + (size_t)b_ * kL;                                \
    const int* mk_ = mask + (size_t)(n) * kL;                                  \
    _Pragma("unroll")                                                          \
    for (int c = 0; c < 5; ++c) { MK[c] = mk_[4*c + grp]; RP[c] = rp_[4*c + grp]; } \
    bool any_ = false;                                                         \
    _Pragma("unroll")                                                          \
    for (int c = 0; c < 5; ++c) any_ |= (MK[c] == 0);                          \
    AM = (__ballot(any_) == 0ull);                                             \
} while (0)

// ---- stage q,k for row n into LDS: 10 global_load_lds_dwordx4, BRANCHLESS.
//      Masked lanes read the dummy line instead (LDS gets garbage; the dot
//      result for those l is overwritten with kNegInf before use). ----
#define ISSUE_QK(MK, n, LQ, LK) do {                                           \
    const size_t rb_ = (size_t)(n) * (kL * kD);                                \
    const float4* qb_ = (const float4*)(q + rb_);                              \
    const float4* kb_ = (const float4*)(k + rb_);                              \
    _Pragma("unroll")                                                          \
    for (int c = 0; c < 5; ++c) {                                              \
        const bool on_ = (MK[c] == 0);                                         \
        const float4* qs_ = on_ ? (qb_ + 64*c + lane) : (dummy + lane);        \
        const float4* ks_ = on_ ? (kb_ + 64*c + lane) : (dummy + lane);        \
        gld_lds16(qs_, (LQ) + c*256);                                          \
        gld_lds16(ks_, (LK) + c*256);                                          \
    }                                                                          \
} while (0)

// ---- one row: wait, v-load, meta-prefetch, dot(LDS), softmax, PV, store,
//      rotate meta, issue stage(i+2).  31 vmem when DOMETA&&DOISSUE. ----
#define BODY(MK, RP, AM, LQ, LK, ncur, WLIT, DOMETA, DOISSUE) do {             \
    const int n_ = (ncur);                                                     \
    WAITCNT_SB(WLIT);                                                          \
    /* v loads (5 vmem, BRANCHLESS): clamped address + value select to 0 */    \
    float4 vv_[5];                                                             \
    { const float4* vb_ = (const float4*)(v + (size_t)n_ * (kL * kD));         \
      _Pragma("unroll")                                                        \
      for (int c = 0; c < 5; ++c) {                                            \
          const bool want_ = (MK[c] == 0) || AM;                               \
          const float4* vs_ = want_ ? (vb_ + 64*c + lane) : (dummy + lane);    \
          const float4 t_ = *vs_;                                              \
          vv_[c].x = want_ ? t_.x : 0.f;                                       \
          vv_[c].y = want_ ? t_.y : 0.f;                                       \
          vv_[c].z = want_ ? t_.z : 0.f;                                       \
          vv_[c].w = want_ ? t_.w : 0.f;                                       \
      } }                                                                      \
    /* meta prefetch for row n+2*GW (10 vmem, unconditional) */                \
    int mn_[5]; float rn_[5];                                                  \
    if (DOMETA) {                                                              \
        const int nn_ = n_ + 2 * GW;                                           \
        const float* rp2_ = r_pri + (size_t)(nn_ & (kB - 1)) * kL;             \
        const int* mk2_ = mask + (size_t)nn_ * kL;                             \
        _Pragma("unroll")                                                      \
        for (int c = 0; c < 5; ++c) { mn_[c] = mk2_[4*c + grp]; rn_[c] = rp2_[4*c + grp]; } \
    }                                                                          \
    /* dot from LDS (ds_read_b128), mask/scale */                              \
    float x_[5];                                                               \
    { const float4* lq_ = (const float4*)(LQ);                                 \
      const float4* lk_ = (const float4*)(LK);                                 \
      _Pragma("unroll")                                                        \
      for (int c = 0; c < 5; ++c) {                                            \
          const float4 a_ = lq_[64*c + lane];                                  \
          const float4 b2_ = lk_[64*c + lane];                                 \
          float p_ = a_.x*b2_.x + a_.y*b2_.y + a_.z*b2_.z + a_.w*b2_.w;        \
          p_ += __shfl_xor(p_, 1);                                             \
          p_ += __shfl_xor(p_, 2);                                             \
          p_ += __shfl_xor(p_, 4);                                             \
          p_ += __shfl_xor(p_, 8);                                             \
          x_[c] = (MK[c] != 0) ? kNegInf : (p_ * RP[c] * kInvTemp);            \
      } }                                                                      \
    /* softmax over 20 l */                                                    \
    float m_ = x_[0];                                                          \
    _Pragma("unroll")                                                          \
    for (int c = 1; c < 5; ++c) m_ = fmaxf(m_, x_[c]);                         \
    m_ = fmaxf(m_, __shfl_xor(m_, 16));                                        \
    m_ = fmaxf(m_, __shfl_xor(m_, 32));                                        \
    float w_[5]; float s_ = 0.f;                                               \
    _Pragma("unroll")                                                          \
    for (int c = 0; c < 5; ++c) { w_[c] = __expf(x_[c] - m_); s_ += w_[c]; }   \
    s_ += __shfl_xor(s_, 16);                                                  \
    s_ += __shfl_xor(s_, 32);                                                  \
    const float is_ = 1.0f / s_;                                               \
    _Pragma("unroll")                                                          \
    for (int c = 0; c < 5; ++c) w_[c] *= is_;                                  \
    /* PV */                                                                   \
    float4 acc_ = {0.f, 0.f, 0.f, 0.f};                                        \
    _Pragma("unroll")                                                          \
    for (int c = 0; c < 5; ++c) {                                              \
        acc_.x += w_[c] * vv_[c].x; acc_.y += w_[c] * vv_[c].y;                \
        acc_.z += w_[c] * vv_[c].z; acc_.w += w_[c] * vv_[c].w;                \
    }                                                                          \
    acc_.x += __shfl_xor(acc_.x, 16); acc_.x += __shfl_xor(acc_.x, 32);        \
    acc_.y += __shfl_xor(acc_.y, 16); acc_.y += __shfl_xor(acc_.y, 32);        \
    acc_.z += __shfl_xor(acc_.z, 16); acc_.z += __shfl_xor(acc_.z, 32);        \
    acc_.w += __shfl_xor(acc_.w, 16); acc_.w += __shfl_xor(acc_.w, 32);        \
    /* stores (6 vmem; exec never empty: grp==0 / sub==c cover lanes) */       \
    if (grp == 0) ((float4*)(out + (size_t)n_ * kD))[sub] = acc_;              \
    _Pragma("unroll")                                                          \
    for (int c = 0; c < 5; ++c) {                                              \
        if (sub == c) attn_out[(size_t)n_ * kL + 4*c + grp] = w_[c];           \
    }                                                                          \
    /* rotate meta + ballot, then issue stage(i+2) (10 vmem) */                \
    if (DOMETA) {                                                              \
        _Pragma("unroll")                                                      \
        for (int c = 0; c < 5; ++c) { MK[c] = mn_[c]; RP[c] = rn_[c]; }        \
        bool any2_ = false;                                                    \
        _Pragma("unroll")                                                      \
        for (int c = 0; c < 5; ++c) any2_ |= (MK[c] == 0);                     \
        AM = (__ballot(any2_) == 0ull);                                        \
    }                                                                          \
    if (DOISSUE) { ISSUE_QK(MK, n_ + 2 * GW, LQ, LK); }                        \
} while (0)

__global__ __launch_bounds__(64) void sdpa_pipe_kernel(
    const float* __restrict__ q,
    const float* __restrict__ k,
    const float* __restrict__ v,
    const float* __restrict__ r_pri,
    const int* __restrict__ mask,
    const float4* __restrict__ dummy,  // 1 KB clamp target for masked lanes
    float* __restrict__ out,           // [N, D]
    float* __restrict__ attn_out,      // [N, L]
    int N)
{
    const int lane = threadIdx.x;     // 1 wave per block
    const int sub = lane & 15;
    const int grp = lane >> 4;
    const int g = blockIdx.x;         // global wave id
    const int GW = (int)gridDim.x;    // total waves; rows per wave = 32

    // LDS ring: [parity][q/k][20*64 floats] = 20 KB -> 8 blocks/CU
    __shared__ float s_qk[2][2][kL * kD];
    float* lq0 = &s_qk[0][0][0]; float* lk0 = &s_qk[0][1][0];
    float* lq1 = &s_qk[1][0][0]; float* lk1 = &s_qk[1][1][0];

    int mklE[5]; float rplE[5]; bool amE;
    int mklO[5]; float rplO[5]; bool amO;

    const int n0 = g;

    // ---- prologue: meta+stage for rows 0 and 1 of this wave ----
    LOAD_META_TO(mklE, rplE, amE, n0);
    ISSUE_QK(mklE, n0, lq0, lk0);               // stage(0) -> buf0
    LOAD_META_TO(mklO, rplO, amO, n0 + GW);     // consumed here (ballot)
    ISSUE_QK(mklO, n0 + GW, lq1, lk1);          // stage(1) -> buf1
    // outstanding at body0: stage0(10) + metaO(drained by ballot) + stage1(10)
    // -> wait(20) lets stage0 land while stage1 stays in flight.

    int n = n0;
    BODY(mklE, rplE, amE, lq0, lk0, n,      20, true, true);   // body 0
    BODY(mklO, rplO, amO, lq1, lk1, n + GW, 31, true, true);   // body 1
    n += 2 * GW;
#pragma unroll 1
    for (int it = 1; it <= kRowsPerWave / 2 - 2; ++it) {       // bodies 2..29
        BODY(mklE, rplE, amE, lq0, lk0, n,      31, true, true);
        BODY(mklO, rplO, amO, lq1, lk1, n + GW, 31, true, true);
        n += 2 * GW;
    }
    BODY(mklE, rplE, amE, lq0, lk0, n,      31, false, false); // body 30
    BODY(mklO, rplO, amO, lq1, lk1, n + GW, 11, false, false); // body 31
}

// ---- fallback: R3 single-row kernel (used only if N % 32 != 0) ----
__global__ __launch_bounds__(256) void sdpa_prior_mask_kernel(
    const float* __restrict__ q,
    const float* __restrict__ k,
    const float* __restrict__ v,
    const float* __restrict__ r_pri,
    const int* __restrict__ mask,
    float* __restrict__ out,
    float* __restrict__ attn_out,
    int N)
{
    const int wave = threadIdx.x >> 6;
    const int lane = threadIdx.x & 63;
    const int n = blockIdx.x * 4 + wave;
    if (n >= N) return;
    const int sub = lane & 15;
    const int grp = lane >> 4;

    const size_t row_base = (size_t)n * kL * kD;
    const float4* qb = (const float4*)(q + row_base);
    const float4* kb = (const float4*)(k + row_base);
    const float4* vb = (const float4*)(v + row_base);
    const float* rp = r_pri + (size_t)(n & (kB - 1)) * kL;
    const int* mk = mask + (size_t)n * kL;

    float rpl[5]; int mkl[5];
#pragma unroll
    for (int c = 0; c < 5; ++c) { mkl[c] = mk[4*c + grp]; rpl[c] = rp[4*c + grp]; }
    bool anyu = false;
#pragma unroll
    for (int c = 0; c < 5; ++c) anyu |= (mkl[c] == 0);
    const bool am = (__ballot(anyu) == 0ull);

    float4 qv[5], kv[5], vv[5];
#pragma unroll
    for (int c = 0; c < 5; ++c) {
        qv[c] = make_float4(0.f,0.f,0.f,0.f);
        kv[c] = make_float4(0.f,0.f,0.f,0.f);
        vv[c] = make_float4(0.f,0.f,0.f,0.f);
        if (mkl[c] == 0) { qv[c] = qb[64*c + lane]; kv[c] = kb[64*c + lane]; }
        if (mkl[c] == 0 || am) vv[c] = vb[64*c + lane];
    }
    float x[5];
#pragma unroll
    for (int c = 0; c < 5; ++c) {
        float p = qv[c].x*kv[c].x + qv[c].y*kv[c].y + qv[c].z*kv[c].z + qv[c].w*kv[c].w;
        p += __shfl_xor(p, 1); p += __shfl_xor(p, 2);
        p += __shfl_xor(p, 4); p += __shfl_xor(p, 8);
        x[c] = (mkl[c] != 0) ? kNegInf : (p * rpl[c] * kInvTemp);
    }
    float m = x[0];
#pragma unroll
    for (int c = 1; c < 5; ++c) m = fmaxf(m, x[c]);
    m = fmaxf(m, __shfl_xor(m, 16)); m = fmaxf(m, __shfl_xor(m, 32));
    float w[5]; float s = 0.f;
#pragma unroll
    for (int c = 0; c < 5; ++c) { w[c] = __expf(x[c] - m); s += w[c]; }
    s += __shfl_xor(s, 16); s += __shfl_xor(s, 32);
    const float inv_s = 1.0f / s;
#pragma unroll
    for (int c = 0; c < 5; ++c) w[c] *= inv_s;
    float4 acc = {0.f,0.f,0.f,0.f};
#pragma unroll
    for (int c = 0; c < 5; ++c) {
        acc.x += w[c]*vv[c].x; acc.y += w[c]*vv[c].y;
        acc.z += w[c]*vv[c].z; acc.w += w[c]*vv[c].w;
    }
    acc.x += __shfl_xor(acc.x,16); acc.x += __shfl_xor(acc.x,32);
    acc.y += __shfl_xor(acc.y,16); acc.y += __shfl_xor(acc.y,32);
    acc.z += __shfl_xor(acc.z,16); acc.z += __shfl_xor(acc.z,32);
    acc.w += __shfl_xor(acc.w,16); acc.w += __shfl_xor(acc.w,32);
    if (grp == 0) ((float4*)(out + (size_t)n * kD))[sub] = acc;
#pragma unroll
    for (int c = 0; c < 5; ++c) {
        if (sub == c) attn_out[(size_t)n * kL + 4*c + grp] = w[c];
    }
}

extern "C" void kernel_launch(void* const* d_in, const int* in_sizes, int n_in,
                              void* d_out, int out_size, void* d_ws, size_t ws_size,
                              hipStream_t stream) {
    const float* q = (const float*)d_in[0];
    const float* k = (const float*)d_in[1];
    const float* v = (const float*)d_in[2];
    const float* r_pri = (const float*)d_in[3];
    const int* mask = (const int*)d_in[4];

    const int N = in_sizes[0] / (kL * kD);  // 65536
    float* out = (float*)d_out;
    float* attn = out + (size_t)N * kD;

    if (N % kRowsPerWave == 0) {
        // clamp target for masked lanes: 1 KB of workspace (contents ignored),
        // falling back to q's first 1 KB if no workspace is provided.
        const float4* dummy = (d_ws != nullptr && ws_size >= 1024)
                                  ? (const float4*)d_ws : (const float4*)q;
        const int waves = N / kRowsPerWave;   // 2048 for N=65536
        dim3 block(64);
        dim3 grid(waves);                     // 1 wave/block, 8 blocks/CU (LDS)
        hipLaunchKernelGGL(sdpa_pipe_kernel, grid, block, 0, stream,
                           q, k, v, r_pri, mask, dummy, out, attn, N);
    } else {
        dim3 block(256);
        dim3 grid((N + 3) / 4);
        hipLaunchKernelGGL(sdpa_prior_mask_kernel, grid, block, 0, stream,
                           q, k, v, r_pri, mask, out, attn, N);
    }
}

// Round 5
// 730.990 us; speedup vs baseline: 1.0136x; 1.0136x over previous
//
#include <hip/hip_runtime.h>

// ScaledDotProductAttention with per-neighbor prior reweighting + mask.
// Shapes: q,k,v [N=65536, L=20, D=64] f32; r_pri [B=32768, L]; mask [N, L] (int).
// out = concat(output [N,D], attn [N,L]) f32.
//
// One 64-lane wave per row n. lane = grp*16 + sub.
//   chunk c in [0,5): l = 4c + grp; float4 index = 64c + lane -> each wave-load
//   covers 4 consecutive l-rows = 1024 contiguous bytes. Fully coalesced.
//
// R3 (best verified: ~162 us kernel / 731.0 us harness): mask-predicated loads.
// mask = Bernoulli(0.5); a masked l has w[l] == 0 EXACTLY in f32 (exp(-1e10 - m)
// underflows for any finite m from unmasked entries), so q[l], k[l], v[l] are
// never needed. Load mask (5 MB, L3-resident) first, then issue q/k/v loads
// only for unmasked l-rows: ~50% of the 1.01 GB input stream skipped.
// Fully-masked-row edge case (ballot==0): softmax is uniform -> needs ALL of v
// (but still no q/k), handled by widening the v-predicate.
//
// R4 (reg A/B pipeline), R6 (global_load_lds DMA ring, counted vmcnt, 8
// waves/CU) were both neutral-to-worse (170/172 us). Three structurally
// different issue schedules and a 3x occupancy spread converge at 162-172 us
// -> the limiter is the memory system's service rate for this predicated
// stream (~3.2 TB/s), not per-wave issue structure. R3 is the minimum-overhead
// expression of that stream; restored here.

namespace {
constexpr int kL = 20;
constexpr int kD = 64;
constexpr int kB = 32768;
constexpr float kNegInf = -1e10f;
constexpr float kInvTemp = 0.125f;  // 1 / TEMPERATURE(=8)
}

__global__ __launch_bounds__(256) void sdpa_prior_mask_kernel(
    const float* __restrict__ q,
    const float* __restrict__ k,
    const float* __restrict__ v,
    const float* __restrict__ r_pri,
    const int* __restrict__ mask,
    float* __restrict__ out,       // [N, D]
    float* __restrict__ attn_out,  // [N, L]
    int N)
{
    const int wave = threadIdx.x >> 6;
    const int lane = threadIdx.x & 63;
    const int n = blockIdx.x * 4 + wave;
    if (n >= N) return;

    const int sub = lane & 15;  // which float4 within the 64-wide d-row
    const int grp = lane >> 4;  // l offset within a 4-row chunk

    const size_t row_base = (size_t)n * kL * kD;
    const float4* qb = (const float4*)(q + row_base);
    const float4* kb = (const float4*)(k + row_base);
    const float4* vb = (const float4*)(v + row_base);
    const int b = n & (kB - 1);
    const float* rp = r_pri + (size_t)b * kL;
    const int* mk = mask + (size_t)n * kL;

    // ---- mask + prior first (tiny, L3-resident: gates everything else) ----
    float rpl[5];
    int mkl[5];
#pragma unroll
    for (int c = 0; c < 5; ++c) {
        const int l = 4 * c + grp;
        mkl[c] = mk[l];
        rpl[c] = rp[l];
    }

    bool any_unmasked = false;
#pragma unroll
    for (int c = 0; c < 5; ++c) any_unmasked |= (mkl[c] == 0);
    const bool all_masked = (__ballot(any_unmasked) == 0ull);

    // ---- predicated q/k loads: only unmasked l-rows contribute logits ----
    float4 qv[5], kv[5];
#pragma unroll
    for (int c = 0; c < 5; ++c) {
        qv[c] = make_float4(0.f, 0.f, 0.f, 0.f);
        kv[c] = make_float4(0.f, 0.f, 0.f, 0.f);
        if (mkl[c] == 0) {
            const int idx = 64 * c + lane;
            qv[c] = qb[idx];
            kv[c] = kb[idx];
        }
    }

    // ---- logits: x[c] = masked, scaled dot(q[l], k[l]) for l = 4c + grp ----
    float x[5];
#pragma unroll
    for (int c = 0; c < 5; ++c) {
        float p = qv[c].x * kv[c].x + qv[c].y * kv[c].y +
                  qv[c].z * kv[c].z + qv[c].w * kv[c].w;
        // reduce across the 16 sub-lanes (same l)
        p += __shfl_xor(p, 1);
        p += __shfl_xor(p, 2);
        p += __shfl_xor(p, 4);
        p += __shfl_xor(p, 8);
        const float scaled = p * rpl[c] * kInvTemp;
        x[c] = (mkl[c] != 0) ? kNegInf : scaled;
    }

    // ---- predicated v loads, issued BEFORE the softmax shuffle chain so their
    // latency hides under it (q/k registers are dead after the logit loop) ----
    float4 vv[5];
#pragma unroll
    for (int c = 0; c < 5; ++c) {
        vv[c] = make_float4(0.f, 0.f, 0.f, 0.f);
        if ((mkl[c] == 0) || all_masked) {
            vv[c] = vb[64 * c + lane];
        }
    }

    // ---- softmax over all 20 l (each lane holds 5; union over 4 grps = 20) ----
    float m = x[0];
#pragma unroll
    for (int c = 1; c < 5; ++c) m = fmaxf(m, x[c]);
    m = fmaxf(m, __shfl_xor(m, 16));
    m = fmaxf(m, __shfl_xor(m, 32));

    float w[5];
    float s = 0.f;
#pragma unroll
    for (int c = 0; c < 5; ++c) {
        w[c] = __expf(x[c] - m);
        s += w[c];
    }
    s += __shfl_xor(s, 16);
    s += __shfl_xor(s, 32);
    const float inv_s = 1.0f / s;
#pragma unroll
    for (int c = 0; c < 5; ++c) w[c] *= inv_s;

    // ---- output: out[n, d] = sum_l w[l] * v[n, l, d] ----
    // (skipped v rows have w == 0 and vv == 0: contribute nothing, no NaNs)
    float4 acc = {0.f, 0.f, 0.f, 0.f};
#pragma unroll
    for (int c = 0; c < 5; ++c) {
        acc.x += w[c] * vv[c].x;
        acc.y += w[c] * vv[c].y;
        acc.z += w[c] * vv[c].z;
        acc.w += w[c] * vv[c].w;
    }
    // sum partial outputs across the 4 grps (same d-range, different l-sets)
    acc.x += __shfl_xor(acc.x, 16);
    acc.x += __shfl_xor(acc.x, 32);
    acc.y += __shfl_xor(acc.y, 16);
    acc.y += __shfl_xor(acc.y, 32);
    acc.z += __shfl_xor(acc.z, 16);
    acc.z += __shfl_xor(acc.z, 32);
    acc.w += __shfl_xor(acc.w, 16);
    acc.w += __shfl_xor(acc.w, 32);

    if (grp == 0) {
        ((float4*)(out + (size_t)n * kD))[sub] = acc;
    }

    // ---- attn probabilities: attn_out[n, l] ----
    // lane (grp, sub) holds w[c] for l = 4c + grp; let sub==c lanes write.
#pragma unroll
    for (int c = 0; c < 5; ++c) {
        if (sub == c) attn_out[(size_t)n * kL + 4 * c + grp] = w[c];
    }
}

extern "C" void kernel_launch(void* const* d_in, const int* in_sizes, int n_in,
                              void* d_out, int out_size, void* d_ws, size_t ws_size,
                              hipStream_t stream) {
    const float* q = (const float*)d_in[0];
    const float* k = (const float*)d_in[1];
    const float* v = (const float*)d_in[2];
    const float* r_pri = (const float*)d_in[3];
    const int* mask = (const int*)d_in[4];

    const int N = in_sizes[0] / (kL * kD);  // 65536
    float* out = (float*)d_out;
    float* attn = out + (size_t)N * kD;

    dim3 block(256);
    dim3 grid((N + 3) / 4);  // 4 rows (waves) per block
    hipLaunchKernelGGL(sdpa_prior_mask_kernel, grid, block, 0, stream,
                       q, k, v, r_pri, mask, out, attn, N);
}